// Round 7
// baseline (396.300 us; speedup 1.0000x reference)
//
#include <hip/hip_runtime.h>

#define Bn 4
#define Hn 16
#define Sn 2048
#define Dn 64
#define NT (Sn / 64)
#define BLOB 24576
#define WS_NEED ((size_t)Bn * Hn * NT * BLOB)

typedef __attribute__((ext_vector_type(8))) short bf16x8;
typedef __attribute__((ext_vector_type(4))) float f32x4;
typedef __attribute__((ext_vector_type(4))) float float4_t;

__device__ __forceinline__ short f2bf(float f) {
    union { float f; unsigned u; } v; v.f = f;
    unsigned r = v.u + 0x7fffu + ((v.u >> 16) & 1u);
    return (short)(r >> 16);
}
__device__ __forceinline__ float bf2f(short h) {
    union { unsigned u; float f; } v; v.u = ((unsigned)(unsigned short)h) << 16;
    return v.f;
}

// ---------------- pre-pass: K -> (hi,lo) bf16, V -> V^T bf16, in LDS-image layout ----------------
// blob[bh*NT + t] (24 KB): [0,8K) K-hi swizzled, [8K,16K) K-lo swizzled, [16K,24K) V^T swizzled
__global__ __launch_bounds__(256) void prepass_kernel(
    const float* __restrict__ K, const float* __restrict__ V, char* __restrict__ ws)
{
    const int tid = threadIdx.x;
    const int kv0 = (blockIdx.x & (NT - 1)) * 64;
    char* blob = ws + (size_t)blockIdx.x * BLOB;
    const size_t kv_base = (size_t)(blockIdx.x >> 5) * Sn * Dn;

    {
        const int r  = tid >> 2;
        const int dc = (tid & 3) * 16;
        const float* krow = K + kv_base + (size_t)(kv0 + r) * Dn + dc;
        float4_t k0 = ((const float4_t*)krow)[0];
        float4_t k1 = ((const float4_t*)krow)[1];
        float4_t k2 = ((const float4_t*)krow)[2];
        float4_t k3 = ((const float4_t*)krow)[3];
        float fv[16] = {k0[0],k0[1],k0[2],k0[3], k1[0],k1[1],k1[2],k1[3],
                        k2[0],k2[1],k2[2],k2[3], k3[0],k3[1],k3[2],k3[3]};
        bf16x8 ha, hb, la, lb;
#pragma unroll
        for (int j = 0; j < 8; ++j) {
            short h = f2bf(fv[j]);
            ha[j] = h; la[j] = f2bf(fv[j] - bf2f(h));
            short h2 = f2bf(fv[j + 8]);
            hb[j] = h2; lb[j] = f2bf(fv[j + 8] - bf2f(h2));
        }
        const unsigned base = (unsigned)(r * 128 + dc * 2);
        const unsigned swz  = (unsigned)((r & 7) << 4);
        *(bf16x8*)(blob + ((base) ^ swz))             = ha;
        *(bf16x8*)(blob + ((base + 16) ^ swz))        = hb;
        *(bf16x8*)(blob + 8192 + ((base) ^ swz))      = la;
        *(bf16x8*)(blob + 8192 + ((base + 16) ^ swz)) = lb;
    }
    {
        const int r2 = (tid & 31) * 2;
        const int d0 = (tid >> 5) * 8;
        const float* v0 = V + kv_base + (size_t)(kv0 + r2) * Dn + d0;
        float4_t a0 = ((const float4_t*)v0)[0];
        float4_t a1 = ((const float4_t*)v0)[1];
        float4_t b0 = ((const float4_t*)(v0 + Dn))[0];
        float4_t b1 = ((const float4_t*)(v0 + Dn))[1];
        float av[8] = {a0[0],a0[1],a0[2],a0[3], a1[0],a1[1],a1[2],a1[3]};
        float bv[8] = {b0[0],b0[1],b0[2],b0[3], b1[0],b1[1],b1[2],b1[3]};
#pragma unroll
        for (int j = 0; j < 8; ++j) {
            const int d = d0 + j;
            unsigned wv = ((unsigned)(unsigned short)f2bf(av[j]))
                        | (((unsigned)(unsigned short)f2bf(bv[j])) << 16);
            unsigned off = ((unsigned)(d * 128 + r2 * 2)) ^ ((unsigned)((d & 7) << 4));
            *(unsigned*)(blob + 16384 + off) = wv;
        }
    }
}

// ---------------- main attention kernel: R5 sync regime, 2 q-subtiles (32 rows) per wave ----------
// Fixed-base softmax (p = exp2(s), sqrt(2)*log2e folded into Q). K/V LDS fragments read once,
// feed both q-subtiles -> DS reads per q-row nearly halved vs R5; staging traffic halved.
__global__ __launch_bounds__(256, 2) void attn_main_kernel(
    const float* __restrict__ Q, const float* __restrict__ Msk,
    const char* __restrict__ ws, float* __restrict__ Out)
{
    __shared__ char lds_kv[2][BLOB];               // double-buffered tile blob
    __shared__ unsigned short lds_p[4][32 * 64];   // per-wave P tile (wave-private, 4 KB)

    const int tid  = threadIdx.x;
    const int lane = tid & 63;
    const int w    = tid >> 6;
    const int lq   = lane & 15;
    const int lg   = lane >> 4;

    const int q0 = blockIdx.x * 128;
    const int qw = q0 + w * 32;
    const int bh = blockIdx.y;

    const float* qp    = Q + (size_t)bh * Sn * Dn;
    const float* mbase = Msk + (size_t)bh * Sn * Sn + (size_t)qw * Sn;
    const char*  ws_bh = ws + (size_t)bh * NT * BLOB;
    float*       op    = Out + (size_t)bh * Sn * Dn + (size_t)qw * Dn;

    const float QSCALE = 2.0402789f;  // sqrt(2) * log2(e): logits in log2 domain

    // ---- Q fragments hi/lo for both subtiles, pre-scaled ----
    bf16x8 qh[2][2], qlo[2][2];
#pragma unroll
    for (int a = 0; a < 2; ++a) {
        const float* qrow = qp + (size_t)(qw + a * 16 + lq) * Dn + lg * 8;
#pragma unroll
        for (int c = 0; c < 2; ++c) {
            float4_t f0 = *(const float4_t*)(qrow + c * 32);
            float4_t f1 = *(const float4_t*)(qrow + c * 32 + 4);
            float fv[8] = {f0[0], f0[1], f0[2], f0[3], f1[0], f1[1], f1[2], f1[3]};
            bf16x8 th, tl;
#pragma unroll
            for (int j = 0; j < 8; ++j) {
                float x = fv[j] * QSCALE;
                short h = f2bf(x);
                th[j] = h;
                tl[j] = f2bf(x - bf2f(h));
            }
            qh[a][c] = th; qlo[a][c] = tl;
        }
    }

    float l_st[2][4];
    f32x4 o_acc[2][4];
#pragma unroll
    for (int a = 0; a < 2; ++a)
#pragma unroll
        for (int r = 0; r < 4; ++r) {
            l_st[a][r] = 0.0f;
            o_acc[a][r] = (f32x4){0.f, 0.f, 0.f, 0.f};
        }

#define STAGE(TSRC, BUFIDX) do {                                                   \
        const char* _src = ws_bh + (size_t)(TSRC) * BLOB + w * 6144 + lane * 16;   \
        char* _dst = &lds_kv[BUFIDX][w * 6144];                                    \
        _Pragma("unroll")                                                          \
        for (int _i = 0; _i < 6; ++_i) {                                           \
            __builtin_amdgcn_global_load_lds(                                      \
                (const __attribute__((address_space(1))) void*)(_src + _i * 1024), \
                (__attribute__((address_space(3))) void*)(_dst + _i * 1024),       \
                16, 0, 0);                                                         \
        }                                                                          \
    } while (0)

#define LOADMASK(MREG, TSRC) do {                                                        \
        _Pragma("unroll")                                                                \
        for (int _a = 0; _a < 2; ++_a)                                                   \
        _Pragma("unroll")                                                                \
        for (int _r = 0; _r < 4; ++_r)                                                   \
        _Pragma("unroll")                                                                \
        for (int _kt = 0; _kt < 4; ++_kt)                                                \
            MREG[_a][_r * 4 + _kt] =                                                     \
                mbase[(size_t)(_a * 16 + lg * 4 + _r) * Sn + (TSRC) * 64 + _kt * 16 + lq]; \
    } while (0)

#define ITER_BODY(T, BUF, MU, MP) do {                                                   \
        __syncthreads(); /* implicit vmcnt(0): tile-T staging + mask(T) regs arrived */  \
        if ((T) + 1 < NT) {                                                              \
            STAGE((T) + 1, (BUF) ^ 1);                                                   \
            LOADMASK(MP, (T) + 1);                                                       \
        }                                                                                \
        const char* kb = lds_kv[BUF];                                                    \
        f32x4 s[2][4];                                                                   \
        _Pragma("unroll")                                                                \
        for (int kt = 0; kt < 4; ++kt) {                                                 \
            f32x4 a0 = (f32x4){0.f, 0.f, 0.f, 0.f};                                      \
            f32x4 a1 = (f32x4){0.f, 0.f, 0.f, 0.f};                                      \
            _Pragma("unroll")                                                            \
            for (int c = 0; c < 2; ++c) {                                                \
                const int krow = kt * 16 + lq;                                           \
                unsigned off = ((unsigned)(krow * 128 + (c * 32 + lg * 8) * 2))          \
                             ^ ((unsigned)((krow & 7) << 4));                            \
                bf16x8 khf = *(const bf16x8*)(kb + off);                                 \
                bf16x8 klf = *(const bf16x8*)(kb + 8192 + off);                          \
                a0 = __builtin_amdgcn_mfma_f32_16x16x32_bf16(qh[0][c],  khf, a0, 0,0,0); \
                a0 = __builtin_amdgcn_mfma_f32_16x16x32_bf16(qh[0][c],  klf, a0, 0,0,0); \
                a0 = __builtin_amdgcn_mfma_f32_16x16x32_bf16(qlo[0][c], khf, a0, 0,0,0); \
                a1 = __builtin_amdgcn_mfma_f32_16x16x32_bf16(qh[1][c],  khf, a1, 0,0,0); \
                a1 = __builtin_amdgcn_mfma_f32_16x16x32_bf16(qh[1][c],  klf, a1, 0,0,0); \
                a1 = __builtin_amdgcn_mfma_f32_16x16x32_bf16(qlo[1][c], khf, a1, 0,0,0); \
            }                                                                            \
            s[0][kt] = a0; s[1][kt] = a1;                                                \
        }                                                                                \
        /* fixed-base softmax numerator + dropout mask -> wave-private P tile */         \
        {                                                                                \
            unsigned short* pw = &lds_p[w][0];                                           \
            _Pragma("unroll")                                                            \
            for (int a = 0; a < 2; ++a)                                                  \
            _Pragma("unroll")                                                            \
            for (int r = 0; r < 4; ++r) {                                                \
                const int row = a * 16 + lg * 4 + r;                                     \
                float psum = 0.f;                                                        \
                _Pragma("unroll")                                                        \
                for (int kt = 0; kt < 4; ++kt) {                                         \
                    float p = exp2f(s[a][kt][r]);                                        \
                    psum += p;                                                           \
                    float pm = p * MU[a][r * 4 + kt];                                    \
                    unsigned off = ((unsigned)(row * 128 + (kt * 16 + lq) * 2))          \
                                 ^ ((unsigned)((row & 7) << 4));                         \
                    *(unsigned short*)((char*)pw + off) = (unsigned short)f2bf(pm);      \
                }                                                                        \
                l_st[a][r] += psum;                                                      \
            }                                                                            \
        }                                                                                \
        /* PV: P from wave-private LDS (in-order DS pipe), shared V frags */             \
        _Pragma("unroll")                                                                \
        for (int kc = 0; kc < 2; ++kc) {                                                 \
            bf16x8 pa[2];                                                                \
            _Pragma("unroll")                                                            \
            for (int a = 0; a < 2; ++a) {                                                \
                const int prow = a * 16 + lq;                                            \
                unsigned poff = ((unsigned)(prow * 128 + (kc * 32 + lg * 8) * 2))        \
                              ^ ((unsigned)((prow & 7) << 4));                           \
                pa[a] = *(const bf16x8*)((const char*)&lds_p[w][0] + poff);              \
            }                                                                            \
            _Pragma("unroll")                                                            \
            for (int dt = 0; dt < 4; ++dt) {                                             \
                const int drow = dt * 16 + lq;                                           \
                unsigned voff = ((unsigned)(drow * 128 + (kc * 32 + lg * 8) * 2))        \
                              ^ ((unsigned)((drow & 7) << 4));                           \
                bf16x8 vb = *(const bf16x8*)(kb + 16384 + voff);                         \
                o_acc[0][dt] = __builtin_amdgcn_mfma_f32_16x16x32_bf16(pa[0], vb,        \
                                                                o_acc[0][dt], 0, 0, 0);  \
                o_acc[1][dt] = __builtin_amdgcn_mfma_f32_16x16x32_bf16(pa[1], vb,        \
                                                                o_acc[1][dt], 0, 0, 0);  \
            }                                                                            \
        }                                                                                \
    } while (0)

    float mA[2][16], mB[2][16];
    STAGE(0, 0);
    LOADMASK(mA, 0);

    for (int t = 0; t < NT; t += 2) {
        ITER_BODY(t, 0, mA, mB);
        ITER_BODY(t + 1, 1, mB, mA);
    }

#pragma unroll
    for (int a = 0; a < 2; ++a)
#pragma unroll
    for (int r = 0; r < 4; ++r) {
        float ls = l_st[a][r];
        ls += __shfl_xor(ls, 1);
        ls += __shfl_xor(ls, 2);
        ls += __shfl_xor(ls, 4);
        ls += __shfl_xor(ls, 8);
        const float inv = 1.0f / ls;
#pragma unroll
        for (int dt = 0; dt < 4; ++dt) {
            op[(size_t)(a * 16 + lg * 4 + r) * Dn + dt * 16 + lq] = o_acc[a][dt][r] * inv;
        }
    }
#undef STAGE
#undef LOADMASK
#undef ITER_BODY
}

// ---------------- fallback (R2-style self-contained kernel, used if ws too small) ----------------
__global__ __launch_bounds__(256) void attn_drop_fallback(
    const float* __restrict__ Q, const float* __restrict__ K,
    const float* __restrict__ V, const float* __restrict__ Msk,
    float* __restrict__ Out)
{
    __shared__ unsigned short lds_kh[64 * 64];
    __shared__ unsigned short lds_kl[64 * 64];
    __shared__ unsigned short lds_v[64 * 64];
    __shared__ unsigned short lds_p[4][16 * 64];

    const int tid  = threadIdx.x;
    const int lane = tid & 63;
    const int w    = tid >> 6;
    const int lq   = lane & 15;
    const int lg   = lane >> 4;
    const int q0 = blockIdx.x * 64;
    const int bh = blockIdx.y;
    const size_t qkv_base = (size_t)bh * Sn * Dn;
    const float* qp = Q + qkv_base;
    const float* kp = K + qkv_base;
    const float* vp = V + qkv_base;
    const float* mbase = Msk + (size_t)bh * Sn * Sn + (size_t)(q0 + w * 16) * Sn;
    float* op = Out + qkv_base + (size_t)(q0 + w * 16) * Dn;
    const float SQRT2 = 1.41421356237f;
    const float LOG2E = 1.44269504089f;

    bf16x8 qh[2], ql[2];
    {
        const float* qrow = qp + (size_t)(q0 + w * 16 + lq) * Dn + lg * 8;
#pragma unroll
        for (int c = 0; c < 2; ++c) {
            float4_t f0 = *(const float4_t*)(qrow + c * 32);
            float4_t f1 = *(const float4_t*)(qrow + c * 32 + 4);
            float fv[8] = {f0[0], f0[1], f0[2], f0[3], f1[0], f1[1], f1[2], f1[3]};
            bf16x8 th, tl;
#pragma unroll
            for (int j = 0; j < 8; ++j) {
                short h = f2bf(fv[j]);
                th[j] = h; tl[j] = f2bf(fv[j] - bf2f(h));
            }
            qh[c] = th; ql[c] = tl;
        }
    }
    float m_st[4], l_st[4];
    f32x4 o_acc[4];
#pragma unroll
    for (int r = 0; r < 4; ++r) { m_st[r] = -INFINITY; l_st[r] = 0.0f; }
#pragma unroll
    for (int dt = 0; dt < 4; ++dt) o_acc[dt] = (f32x4){0.f, 0.f, 0.f, 0.f};

    for (int t = 0; t < NT; ++t) {
        const int kv0 = t * 64;
        __syncthreads();
        {
            const int r  = tid >> 2;
            const int dc = (tid & 3) * 16;
            const float* krow = kp + (size_t)(kv0 + r) * Dn + dc;
            float4_t k0 = ((const float4_t*)krow)[0];
            float4_t k1 = ((const float4_t*)krow)[1];
            float4_t k2 = ((const float4_t*)krow)[2];
            float4_t k3 = ((const float4_t*)krow)[3];
            float fv[16] = {k0[0],k0[1],k0[2],k0[3], k1[0],k1[1],k1[2],k1[3],
                            k2[0],k2[1],k2[2],k2[3], k3[0],k3[1],k3[2],k3[3]};
            bf16x8 ha, hb, la, lb;
#pragma unroll
            for (int j = 0; j < 8; ++j) {
                short h = f2bf(fv[j]);
                ha[j] = h; la[j] = f2bf(fv[j] - bf2f(h));
                short h2 = f2bf(fv[j + 8]);
                hb[j] = h2; lb[j] = f2bf(fv[j + 8] - bf2f(h2));
            }
            const unsigned base = (unsigned)(r * 128 + dc * 2);
            const unsigned swz  = (unsigned)((r & 7) << 4);
            *(bf16x8*)((char*)lds_kh + ((base) ^ swz))      = ha;
            *(bf16x8*)((char*)lds_kh + ((base + 16) ^ swz)) = hb;
            *(bf16x8*)((char*)lds_kl + ((base) ^ swz))      = la;
            *(bf16x8*)((char*)lds_kl + ((base + 16) ^ swz)) = lb;
        }
        {
            const int r2 = (tid & 31) * 2;
            const int d0 = (tid >> 5) * 8;
            const float* v0 = vp + (size_t)(kv0 + r2) * Dn + d0;
            float4_t a0 = ((const float4_t*)v0)[0];
            float4_t a1 = ((const float4_t*)v0)[1];
            float4_t b0 = ((const float4_t*)(v0 + Dn))[0];
            float4_t b1 = ((const float4_t*)(v0 + Dn))[1];
            float av[8] = {a0[0],a0[1],a0[2],a0[3], a1[0],a1[1],a1[2],a1[3]};
            float bv[8] = {b0[0],b0[1],b0[2],b0[3], b1[0],b1[1],b1[2],b1[3]};
#pragma unroll
            for (int j = 0; j < 8; ++j) {
                const int d = d0 + j;
                unsigned wv = ((unsigned)(unsigned short)f2bf(av[j]))
                            | (((unsigned)(unsigned short)f2bf(bv[j])) << 16);
                unsigned off = ((unsigned)(d * 128 + r2 * 2)) ^ ((unsigned)((d & 7) << 4));
                *(unsigned*)((char*)lds_v + off) = wv;
            }
        }
        __syncthreads();
        f32x4 s[4];
#pragma unroll
        for (int kt = 0; kt < 4; ++kt) {
            f32x4 acc = (f32x4){0.f, 0.f, 0.f, 0.f};
#pragma unroll
            for (int c = 0; c < 2; ++c) {
                const int krow = kt * 16 + lq;
                unsigned off = ((unsigned)(krow * 128 + (c * 32 + lg * 8) * 2))
                             ^ ((unsigned)((krow & 7) << 4));
                bf16x8 khf = *(const bf16x8*)((const char*)lds_kh + off);
                bf16x8 klf = *(const bf16x8*)((const char*)lds_kl + off);
                acc = __builtin_amdgcn_mfma_f32_16x16x32_bf16(qh[c], khf, acc, 0, 0, 0);
                acc = __builtin_amdgcn_mfma_f32_16x16x32_bf16(qh[c], klf, acc, 0, 0, 0);
                acc = __builtin_amdgcn_mfma_f32_16x16x32_bf16(ql[c], khf, acc, 0, 0, 0);
            }
            s[kt] = acc * SQRT2;
        }
        float pbuf[4][4];
#pragma unroll
        for (int r = 0; r < 4; ++r) {
            float mx = fmaxf(fmaxf(s[0][r], s[1][r]), fmaxf(s[2][r], s[3][r]));
            mx = fmaxf(mx, __shfl_xor(mx, 1));
            mx = fmaxf(mx, __shfl_xor(mx, 2));
            mx = fmaxf(mx, __shfl_xor(mx, 4));
            mx = fmaxf(mx, __shfl_xor(mx, 8));
            const float mnew = fmaxf(m_st[r], mx);
            const float corr = exp2f((m_st[r] - mnew) * LOG2E);
            m_st[r] = mnew;
            float psum = 0.f;
#pragma unroll
            for (int kt = 0; kt < 4; ++kt) {
                float p = exp2f((s[kt][r] - mnew) * LOG2E);
                pbuf[kt][r] = p;
                psum += p;
            }
            l_st[r] = l_st[r] * corr + psum;
#pragma unroll
            for (int dt = 0; dt < 4; ++dt) o_acc[dt][r] *= corr;
        }
        {
            unsigned short* pw = &lds_p[w][0];
#pragma unroll
            for (int r = 0; r < 4; ++r) {
                const int row = lg * 4 + r;
                const float* mp = mbase + (size_t)row * Sn + kv0;
#pragma unroll
                for (int kt = 0; kt < 4; ++kt) {
                    float mv = mp[kt * 16 + lq];
                    float pm = pbuf[kt][r] * mv;
                    unsigned off = ((unsigned)(row * 128 + (kt * 16 + lq) * 2))
                                 ^ ((unsigned)((row & 7) << 4));
                    *(unsigned short*)((char*)pw + off) = (unsigned short)f2bf(pm);
                }
            }
        }
        __syncthreads();
#pragma unroll
        for (int kc = 0; kc < 2; ++kc) {
            unsigned poff = ((unsigned)(lq * 128 + (kc * 32 + lg * 8) * 2))
                          ^ ((unsigned)((lq & 7) << 4));
            bf16x8 pa = *(const bf16x8*)((const char*)&lds_p[w][0] + poff);
#pragma unroll
            for (int dt = 0; dt < 4; ++dt) {
                const int drow = dt * 16 + lq;
                unsigned voff = ((unsigned)(drow * 128 + (kc * 32 + lg * 8) * 2))
                              ^ ((unsigned)((drow & 7) << 4));
                bf16x8 vb = *(const bf16x8*)((const char*)lds_v + voff);
                o_acc[dt] = __builtin_amdgcn_mfma_f32_16x16x32_bf16(pa, vb, o_acc[dt], 0, 0, 0);
            }
        }
    }
#pragma unroll
    for (int r = 0; r < 4; ++r) {
        float ls = l_st[r];
        ls += __shfl_xor(ls, 1);
        ls += __shfl_xor(ls, 2);
        ls += __shfl_xor(ls, 4);
        ls += __shfl_xor(ls, 8);
        const float inv = 1.0f / ls;
#pragma unroll
        for (int dt = 0; dt < 4; ++dt) {
            op[(size_t)(lg * 4 + r) * Dn + dt * 16 + lq] = o_acc[dt][r] * inv;
        }
    }
}

extern "C" void kernel_launch(void* const* d_in, const int* in_sizes, int n_in,
                              void* d_out, int out_size, void* d_ws, size_t ws_size,
                              hipStream_t stream) {
    const float* q   = (const float*)d_in[0];
    const float* k   = (const float*)d_in[1];
    const float* v   = (const float*)d_in[2];
    const float* msk = (const float*)d_in[3];
    float* out = (float*)d_out;

    if (ws_size >= WS_NEED) {
        prepass_kernel<<<dim3(Bn * Hn * NT), dim3(256), 0, stream>>>(k, v, (char*)d_ws);
        attn_main_kernel<<<dim3(Sn / 128, Bn * Hn), dim3(256), 0, stream>>>(
            q, msk, (const char*)d_ws, out);
    } else {
        attn_drop_fallback<<<dim3(Sn / 64, Bn * Hn), dim3(256), 0, stream>>>(
            q, k, v, msk, out);
    }
}

// Round 8
// 338.673 us; speedup vs baseline: 1.1702x; 1.1702x over previous
//
#include <hip/hip_runtime.h>

#define Bn 4
#define Hn 16
#define Sn 2048
#define Dn 64
#define NT (Sn / 64)
#define BLOB 24576
#define WS_NEED ((size_t)Bn * Hn * NT * BLOB)

typedef __attribute__((ext_vector_type(8))) short bf16x8;
typedef __attribute__((ext_vector_type(4))) float f32x4;
typedef __attribute__((ext_vector_type(4))) float float4_t;

__device__ __forceinline__ short f2bf(float f) {
    union { float f; unsigned u; } v; v.f = f;
    unsigned r = v.u + 0x7fffu + ((v.u >> 16) & 1u);
    return (short)(r >> 16);
}
__device__ __forceinline__ float bf2f(short h) {
    union { unsigned u; float f; } v; v.u = ((unsigned)(unsigned short)h) << 16;
    return v.f;
}

// ---------------- pre-pass: K -> (hi,lo) bf16, V -> V^T bf16, in LDS-image layout ----------------
// blob[bh*NT + t] (24 KB): [0,8K) K-hi swizzled, [8K,16K) K-lo swizzled, [16K,24K) V^T swizzled
__global__ __launch_bounds__(256) void prepass_kernel(
    const float* __restrict__ K, const float* __restrict__ V, char* __restrict__ ws)
{
    const int tid = threadIdx.x;
    const int kv0 = (blockIdx.x & (NT - 1)) * 64;
    char* blob = ws + (size_t)blockIdx.x * BLOB;
    const size_t kv_base = (size_t)(blockIdx.x >> 5) * Sn * Dn;

    {
        const int r  = tid >> 2;
        const int dc = (tid & 3) * 16;
        const float* krow = K + kv_base + (size_t)(kv0 + r) * Dn + dc;
        float4_t k0 = ((const float4_t*)krow)[0];
        float4_t k1 = ((const float4_t*)krow)[1];
        float4_t k2 = ((const float4_t*)krow)[2];
        float4_t k3 = ((const float4_t*)krow)[3];
        float fv[16] = {k0[0],k0[1],k0[2],k0[3], k1[0],k1[1],k1[2],k1[3],
                        k2[0],k2[1],k2[2],k2[3], k3[0],k3[1],k3[2],k3[3]};
        bf16x8 ha, hb, la, lb;
#pragma unroll
        for (int j = 0; j < 8; ++j) {
            short h = f2bf(fv[j]);
            ha[j] = h; la[j] = f2bf(fv[j] - bf2f(h));
            short h2 = f2bf(fv[j + 8]);
            hb[j] = h2; lb[j] = f2bf(fv[j + 8] - bf2f(h2));
        }
        const unsigned base = (unsigned)(r * 128 + dc * 2);
        const unsigned swz  = (unsigned)((r & 7) << 4);
        *(bf16x8*)(blob + ((base) ^ swz))             = ha;
        *(bf16x8*)(blob + ((base + 16) ^ swz))        = hb;
        *(bf16x8*)(blob + 8192 + ((base) ^ swz))      = la;
        *(bf16x8*)(blob + 8192 + ((base + 16) ^ swz)) = lb;
    }
    {
        const int r2 = (tid & 31) * 2;
        const int d0 = (tid >> 5) * 8;
        const float* v0 = V + kv_base + (size_t)(kv0 + r2) * Dn + d0;
        float4_t a0 = ((const float4_t*)v0)[0];
        float4_t a1 = ((const float4_t*)v0)[1];
        float4_t b0 = ((const float4_t*)(v0 + Dn))[0];
        float4_t b1 = ((const float4_t*)(v0 + Dn))[1];
        float av[8] = {a0[0],a0[1],a0[2],a0[3], a1[0],a1[1],a1[2],a1[3]};
        float bv[8] = {b0[0],b0[1],b0[2],b0[3], b1[0],b1[1],b1[2],b1[3]};
#pragma unroll
        for (int j = 0; j < 8; ++j) {
            const int d = d0 + j;
            unsigned wv = ((unsigned)(unsigned short)f2bf(av[j]))
                        | (((unsigned)(unsigned short)f2bf(bv[j])) << 16);
            unsigned off = ((unsigned)(d * 128 + r2 * 2)) ^ ((unsigned)((d & 7) << 4));
            *(unsigned*)(blob + 16384 + off) = wv;
        }
    }
}

// ---------------- main attention kernel (R5 structure + counted-vmcnt barrier) ----------------
// Fixed-base softmax (p = exp2(s), sqrt(2)*log2e folded into Q).
// Per tile, issue order (pinned by sched_barrier): 6x global_load_lds staging, then 16 mask
// loads. Tile barrier = "s_waitcnt vmcnt(16); s_barrier": drains exactly the staging ops,
// keeps the mask loads in flight (they're consumed mid-tile via compiler-inserted waits).
__global__ __launch_bounds__(256) void attn_main_kernel(
    const float* __restrict__ Q, const float* __restrict__ Msk,
    const char* __restrict__ ws, float* __restrict__ Out)
{
    __shared__ char lds_kv[2][BLOB];               // double-buffered tile blob
    __shared__ unsigned short lds_p[4][16 * 64];   // per-wave P tile (wave-private)

    const int tid  = threadIdx.x;
    const int lane = tid & 63;
    const int w    = tid >> 6;
    const int lq   = lane & 15;
    const int lg   = lane >> 4;

    const int q0 = blockIdx.x * 64;
    const int bh = blockIdx.y;

    const float* qp = Q + (size_t)bh * Sn * Dn;
    const float* mbase = Msk + (size_t)bh * Sn * Sn + (size_t)(q0 + w * 16) * Sn;
    const char* ws_bh = ws + (size_t)bh * NT * BLOB;
    float* op = Out + (size_t)bh * Sn * Dn + (size_t)(q0 + w * 16) * Dn;

    const float QSCALE = 2.0402789f;  // sqrt(2) * log2(e): logits directly in log2 domain

    // ---- Q fragments hi/lo, pre-scaled ----
    bf16x8 qh[2], ql[2];
    {
        const float* qrow = qp + (size_t)(q0 + w * 16 + lq) * Dn + lg * 8;
#pragma unroll
        for (int c = 0; c < 2; ++c) {
            float4_t f0 = *(const float4_t*)(qrow + c * 32);
            float4_t f1 = *(const float4_t*)(qrow + c * 32 + 4);
            float fv[8] = {f0[0], f0[1], f0[2], f0[3], f1[0], f1[1], f1[2], f1[3]};
            bf16x8 th, tl;
#pragma unroll
            for (int j = 0; j < 8; ++j) {
                float x = fv[j] * QSCALE;
                short h = f2bf(x);
                th[j] = h;
                tl[j] = f2bf(x - bf2f(h));
            }
            qh[c] = th; ql[c] = tl;
        }
    }

    float l_st[4];
    f32x4 o_acc[4];
#pragma unroll
    for (int r = 0; r < 4; ++r) l_st[r] = 0.0f;
#pragma unroll
    for (int dt = 0; dt < 4; ++dt) o_acc[dt] = (f32x4){0.f, 0.f, 0.f, 0.f};

#define STAGE(TSRC, BUFIDX) do {                                                   \
        const char* _src = ws_bh + (size_t)(TSRC) * BLOB + w * 6144 + lane * 16;   \
        char* _dst = &lds_kv[BUFIDX][w * 6144];                                    \
        _Pragma("unroll")                                                          \
        for (int _i = 0; _i < 6; ++_i) {                                           \
            __builtin_amdgcn_global_load_lds(                                      \
                (const __attribute__((address_space(1))) void*)(_src + _i * 1024), \
                (__attribute__((address_space(3))) void*)(_dst + _i * 1024),       \
                16, 0, 0);                                                         \
        }                                                                          \
    } while (0)

#define LOADMASK(MREG, TSRC) do {                                                        \
        _Pragma("unroll")                                                                \
        for (int _r = 0; _r < 4; ++_r)                                                   \
        _Pragma("unroll")                                                                \
        for (int _kt = 0; _kt < 4; ++_kt)                                                \
            MREG[_r * 4 + _kt] =                                                         \
                mbase[(size_t)(lg * 4 + _r) * Sn + (TSRC) * 64 + _kt * 16 + lq];         \
    } while (0)

// counted barrier: drain staging (6 oldest VMEM), keep 16 mask loads in flight
#define TILE_BARRIER() do {                                                        \
        asm volatile("s_waitcnt vmcnt(16)\n\ts_barrier" ::: "memory");             \
        __builtin_amdgcn_sched_barrier(0);                                         \
    } while (0)

#define ITER_BODY(T, BUF, MU, MP) do {                                                   \
        TILE_BARRIER(); /* staging(T) drained; mask(T) still in flight */                \
        if ((T) + 1 < NT) {                                                              \
            STAGE((T) + 1, (BUF) ^ 1);                                                   \
            __builtin_amdgcn_sched_barrier(0); /* pin: staging before mask loads */      \
            LOADMASK(MP, (T) + 1);                                                       \
            __builtin_amdgcn_sched_barrier(0); /* pin: mask loads issued here */         \
        }                                                                                \
        const char* kb = lds_kv[BUF];                                                    \
        f32x4 s[4];                                                                      \
        _Pragma("unroll")                                                                \
        for (int kt = 0; kt < 4; ++kt) {                                                 \
            f32x4 acc = (f32x4){0.f, 0.f, 0.f, 0.f};                                     \
            _Pragma("unroll")                                                            \
            for (int c = 0; c < 2; ++c) {                                                \
                const int krow = kt * 16 + lq;                                           \
                unsigned off = ((unsigned)(krow * 128 + (c * 32 + lg * 8) * 2))          \
                             ^ ((unsigned)((krow & 7) << 4));                            \
                bf16x8 khf = *(const bf16x8*)(kb + off);                                 \
                bf16x8 klf = *(const bf16x8*)(kb + 8192 + off);                          \
                acc = __builtin_amdgcn_mfma_f32_16x16x32_bf16(qh[c], khf, acc, 0, 0, 0); \
                acc = __builtin_amdgcn_mfma_f32_16x16x32_bf16(qh[c], klf, acc, 0, 0, 0); \
                acc = __builtin_amdgcn_mfma_f32_16x16x32_bf16(ql[c], khf, acc, 0, 0, 0); \
            }                                                                            \
            s[kt] = acc;                                                                 \
        }                                                                                \
        /* fixed-base softmax numerator: p = exp2(s); no max, no rescale */              \
        {                                                                                \
            unsigned short* pw = &lds_p[w][0];                                           \
            _Pragma("unroll")                                                            \
            for (int r = 0; r < 4; ++r) {                                                \
                const int row = lg * 4 + r;                                              \
                float psum = 0.f;                                                        \
                _Pragma("unroll")                                                        \
                for (int kt = 0; kt < 4; ++kt) {                                         \
                    float p = exp2f(s[kt][r]);                                           \
                    psum += p;                                                           \
                    float pm = p * MU[r * 4 + kt];                                       \
                    unsigned off = ((unsigned)(row * 128 + (kt * 16 + lq) * 2))          \
                                 ^ ((unsigned)((row & 7) << 4));                         \
                    *(unsigned short*)((char*)pw + off) = (unsigned short)f2bf(pm);      \
                }                                                                        \
                l_st[r] += psum;                                                         \
            }                                                                            \
        }                                                                                \
        /* wave-private P: lgkmcnt ordering (compiler-inserted), no barrier needed */    \
        _Pragma("unroll")                                                                \
        for (int kc = 0; kc < 2; ++kc) {                                                 \
            unsigned poff = ((unsigned)(lq * 128 + (kc * 32 + lg * 8) * 2))              \
                          ^ ((unsigned)((lq & 7) << 4));                                 \
            bf16x8 pa = *(const bf16x8*)((const char*)&lds_p[w][0] + poff);              \
            _Pragma("unroll")                                                            \
            for (int dt = 0; dt < 4; ++dt) {                                             \
                const int drow = dt * 16 + lq;                                           \
                unsigned voff = ((unsigned)(drow * 128 + (kc * 32 + lg * 8) * 2))        \
                              ^ ((unsigned)((drow & 7) << 4));                           \
                bf16x8 vb = *(const bf16x8*)(kb + 16384 + voff);                         \
                o_acc[dt] = __builtin_amdgcn_mfma_f32_16x16x32_bf16(pa, vb, o_acc[dt],   \
                                                                    0, 0, 0);            \
            }                                                                            \
        }                                                                                \
    } while (0)

    float mA[16], mB[16];
    STAGE(0, 0);
    __builtin_amdgcn_sched_barrier(0);
    LOADMASK(mA, 0);
    __builtin_amdgcn_sched_barrier(0);

    for (int t = 0; t < NT; t += 2) {
        ITER_BODY(t, 0, mA, mB);
        ITER_BODY(t + 1, 1, mB, mA);
    }

#pragma unroll
    for (int r = 0; r < 4; ++r) {
        float ls = l_st[r];
        ls += __shfl_xor(ls, 1);
        ls += __shfl_xor(ls, 2);
        ls += __shfl_xor(ls, 4);
        ls += __shfl_xor(ls, 8);
        const float inv = 1.0f / ls;
#pragma unroll
        for (int dt = 0; dt < 4; ++dt) {
            op[(size_t)(lg * 4 + r) * Dn + dt * 16 + lq] = o_acc[dt][r] * inv;
        }
    }
#undef STAGE
#undef LOADMASK
#undef TILE_BARRIER
#undef ITER_BODY
}

// ---------------- fallback (R2-style self-contained kernel, used if ws too small) ----------------
__global__ __launch_bounds__(256) void attn_drop_fallback(
    const float* __restrict__ Q, const float* __restrict__ K,
    const float* __restrict__ V, const float* __restrict__ Msk,
    float* __restrict__ Out)
{
    __shared__ unsigned short lds_kh[64 * 64];
    __shared__ unsigned short lds_kl[64 * 64];
    __shared__ unsigned short lds_v[64 * 64];
    __shared__ unsigned short lds_p[4][16 * 64];

    const int tid  = threadIdx.x;
    const int lane = tid & 63;
    const int w    = tid >> 6;
    const int lq   = lane & 15;
    const int lg   = lane >> 4;
    const int q0 = blockIdx.x * 64;
    const int bh = blockIdx.y;
    const size_t qkv_base = (size_t)bh * Sn * Dn;
    const float* qp = Q + qkv_base;
    const float* kp = K + qkv_base;
    const float* vp = V + qkv_base;
    const float* mbase = Msk + (size_t)bh * Sn * Sn + (size_t)(q0 + w * 16) * Sn;
    float* op = Out + qkv_base + (size_t)(q0 + w * 16) * Dn;
    const float SQRT2 = 1.41421356237f;
    const float LOG2E = 1.44269504089f;

    bf16x8 qh[2], ql[2];
    {
        const float* qrow = qp + (size_t)(q0 + w * 16 + lq) * Dn + lg * 8;
#pragma unroll
        for (int c = 0; c < 2; ++c) {
            float4_t f0 = *(const float4_t*)(qrow + c * 32);
            float4_t f1 = *(const float4_t*)(qrow + c * 32 + 4);
            float fv[8] = {f0[0], f0[1], f0[2], f0[3], f1[0], f1[1], f1[2], f1[3]};
            bf16x8 th, tl;
#pragma unroll
            for (int j = 0; j < 8; ++j) {
                short h = f2bf(fv[j]);
                th[j] = h; tl[j] = f2bf(fv[j] - bf2f(h));
            }
            qh[c] = th; ql[c] = tl;
        }
    }
    float m_st[4], l_st[4];
    f32x4 o_acc[4];
#pragma unroll
    for (int r = 0; r < 4; ++r) { m_st[r] = -INFINITY; l_st[r] = 0.0f; }
#pragma unroll
    for (int dt = 0; dt < 4; ++dt) o_acc[dt] = (f32x4){0.f, 0.f, 0.f, 0.f};

    for (int t = 0; t < NT; ++t) {
        const int kv0 = t * 64;
        __syncthreads();
        {
            const int r  = tid >> 2;
            const int dc = (tid & 3) * 16;
            const float* krow = kp + (size_t)(kv0 + r) * Dn + dc;
            float4_t k0 = ((const float4_t*)krow)[0];
            float4_t k1 = ((const float4_t*)krow)[1];
            float4_t k2 = ((const float4_t*)krow)[2];
            float4_t k3 = ((const float4_t*)krow)[3];
            float fv[16] = {k0[0],k0[1],k0[2],k0[3], k1[0],k1[1],k1[2],k1[3],
                            k2[0],k2[1],k2[2],k2[3], k3[0],k3[1],k3[2],k3[3]};
            bf16x8 ha, hb, la, lb;
#pragma unroll
            for (int j = 0; j < 8; ++j) {
                short h = f2bf(fv[j]);
                ha[j] = h; la[j] = f2bf(fv[j] - bf2f(h));
                short h2 = f2bf(fv[j + 8]);
                hb[j] = h2; lb[j] = f2bf(fv[j + 8] - bf2f(h2));
            }
            const unsigned base = (unsigned)(r * 128 + dc * 2);
            const unsigned swz  = (unsigned)((r & 7) << 4);
            *(bf16x8*)((char*)lds_kh + ((base) ^ swz))      = ha;
            *(bf16x8*)((char*)lds_kh + ((base + 16) ^ swz)) = hb;
            *(bf16x8*)((char*)lds_kl + ((base) ^ swz))      = la;
            *(bf16x8*)((char*)lds_kl + ((base + 16) ^ swz)) = lb;
        }
        {
            const int r2 = (tid & 31) * 2;
            const int d0 = (tid >> 5) * 8;
            const float* v0 = vp + (size_t)(kv0 + r2) * Dn + d0;
            float4_t a0 = ((const float4_t*)v0)[0];
            float4_t a1 = ((const float4_t*)v0)[1];
            float4_t b0 = ((const float4_t*)(v0 + Dn))[0];
            float4_t b1 = ((const float4_t*)(v0 + Dn))[1];
            float av[8] = {a0[0],a0[1],a0[2],a0[3], a1[0],a1[1],a1[2],a1[3]};
            float bv[8] = {b0[0],b0[1],b0[2],b0[3], b1[0],b1[1],b1[2],b1[3]};
#pragma unroll
            for (int j = 0; j < 8; ++j) {
                const int d = d0 + j;
                unsigned wv = ((unsigned)(unsigned short)f2bf(av[j]))
                            | (((unsigned)(unsigned short)f2bf(bv[j])) << 16);
                unsigned off = ((unsigned)(d * 128 + r2 * 2)) ^ ((unsigned)((d & 7) << 4));
                *(unsigned*)((char*)lds_v + off) = wv;
            }
        }
        __syncthreads();
        f32x4 s[4];
#pragma unroll
        for (int kt = 0; kt < 4; ++kt) {
            f32x4 acc = (f32x4){0.f, 0.f, 0.f, 0.f};
#pragma unroll
            for (int c = 0; c < 2; ++c) {
                const int krow = kt * 16 + lq;
                unsigned off = ((unsigned)(krow * 128 + (c * 32 + lg * 8) * 2))
                             ^ ((unsigned)((krow & 7) << 4));
                bf16x8 khf = *(const bf16x8*)((const char*)lds_kh + off);
                bf16x8 klf = *(const bf16x8*)((const char*)lds_kl + off);
                acc = __builtin_amdgcn_mfma_f32_16x16x32_bf16(qh[c], khf, acc, 0, 0, 0);
                acc = __builtin_amdgcn_mfma_f32_16x16x32_bf16(qh[c], klf, acc, 0, 0, 0);
                acc = __builtin_amdgcn_mfma_f32_16x16x32_bf16(ql[c], khf, acc, 0, 0, 0);
            }
            s[kt] = acc * SQRT2;
        }
        float pbuf[4][4];
#pragma unroll
        for (int r = 0; r < 4; ++r) {
            float mx = fmaxf(fmaxf(s[0][r], s[1][r]), fmaxf(s[2][r], s[3][r]));
            mx = fmaxf(mx, __shfl_xor(mx, 1));
            mx = fmaxf(mx, __shfl_xor(mx, 2));
            mx = fmaxf(mx, __shfl_xor(mx, 4));
            mx = fmaxf(mx, __shfl_xor(mx, 8));
            const float mnew = fmaxf(m_st[r], mx);
            const float corr = exp2f((m_st[r] - mnew) * LOG2E);
            m_st[r] = mnew;
            float psum = 0.f;
#pragma unroll
            for (int kt = 0; kt < 4; ++kt) {
                float p = exp2f((s[kt][r] - mnew) * LOG2E);
                pbuf[kt][r] = p;
                psum += p;
            }
            l_st[r] = l_st[r] * corr + psum;
#pragma unroll
            for (int dt = 0; dt < 4; ++dt) o_acc[dt][r] *= corr;
        }
        {
            unsigned short* pw = &lds_p[w][0];
#pragma unroll
            for (int r = 0; r < 4; ++r) {
                const int row = lg * 4 + r;
                const float* mp = mbase + (size_t)row * Sn + kv0;
#pragma unroll
                for (int kt = 0; kt < 4; ++kt) {
                    float mv = mp[kt * 16 + lq];
                    float pm = pbuf[kt][r] * mv;
                    unsigned off = ((unsigned)(row * 128 + (kt * 16 + lq) * 2))
                                 ^ ((unsigned)((row & 7) << 4));
                    *(unsigned short*)((char*)pw + off) = (unsigned short)f2bf(pm);
                }
            }
        }
        __syncthreads();
#pragma unroll
        for (int kc = 0; kc < 2; ++kc) {
            unsigned poff = ((unsigned)(lq * 128 + (kc * 32 + lg * 8) * 2))
                          ^ ((unsigned)((lq & 7) << 4));
            bf16x8 pa = *(const bf16x8*)((const char*)&lds_p[w][0] + poff);
#pragma unroll
            for (int dt = 0; dt < 4; ++dt) {
                const int drow = dt * 16 + lq;
                unsigned voff = ((unsigned)(drow * 128 + (kc * 32 + lg * 8) * 2))
                              ^ ((unsigned)((drow & 7) << 4));
                bf16x8 vb = *(const bf16x8*)((const char*)lds_v + voff);
                o_acc[dt] = __builtin_amdgcn_mfma_f32_16x16x32_bf16(pa, vb, o_acc[dt], 0, 0, 0);
            }
        }
    }
#pragma unroll
    for (int r = 0; r < 4; ++r) {
        float ls = l_st[r];
        ls += __shfl_xor(ls, 1);
        ls += __shfl_xor(ls, 2);
        ls += __shfl_xor(ls, 4);
        ls += __shfl_xor(ls, 8);
        const float inv = 1.0f / ls;
#pragma unroll
        for (int dt = 0; dt < 4; ++dt) {
            op[(size_t)(lg * 4 + r) * Dn + dt * 16 + lq] = o_acc[dt][r] * inv;
        }
    }
}

extern "C" void kernel_launch(void* const* d_in, const int* in_sizes, int n_in,
                              void* d_out, int out_size, void* d_ws, size_t ws_size,
                              hipStream_t stream) {
    const float* q   = (const float*)d_in[0];
    const float* k   = (const float*)d_in[1];
    const float* v   = (const float*)d_in[2];
    const float* msk = (const float*)d_in[3];
    float* out = (float*)d_out;

    if (ws_size >= WS_NEED) {
        prepass_kernel<<<dim3(Bn * Hn * NT), dim3(256), 0, stream>>>(k, v, (char*)d_ws);
        attn_main_kernel<<<dim3(Sn / 64, Bn * Hn), dim3(256), 0, stream>>>(
            q, msk, (const char*)d_ws, out);
    } else {
        attn_drop_fallback<<<dim3(Sn / 64, Bn * Hn), dim3(256), 0, stream>>>(
            q, k, v, msk, out);
    }
}